// Round 9
// baseline (549.563 us; speedup 1.0000x reference)
//
#include <hip/hip_runtime.h>
#include <hip/hip_bf16.h>

#define NNODES 50000
#define NEDGES 1600000
#define NF 128
#define NC 40
#define NLAYERS 3
#define NPB 64                               // nodes per bucket
#define NBUCKETS ((NNODES + NPB - 1) / NPB)  // 782
#define NCHUNK 256                           // edge chunks (blocks) for counting sort
#define CE (NEDGES / NCHUNK)                 // 6250 edges per chunk
#define NSC (NBUCKETS * NCHUNK)              // 200192 count entries
#define SELEMS ((size_t)NNODES * 32)         // 1.6M bf16 per feature strip
#define SELEMS2 ((size_t)NNODES * 16)        // in bf162 units

typedef __attribute__((ext_vector_type(8))) short bf16x8_t;  // 8 bf16 = 4 VGPR
typedef __attribute__((ext_vector_type(4))) float f32x4_t;

// ---------------------------------------------------------------------------
// CSR build: deterministic counting sort by bucket (NO global atomics),
// then per-bucket node sort that also emits row_ptr and 4-byte packed edges
// (bf16(w) << 16 | src).
// ---------------------------------------------------------------------------

__global__ __launch_bounds__(1024) void count_kernel(const int* __restrict__ dst,
                                                     int* __restrict__ counts) {
    __shared__ int hist[NBUCKETS];
    int t = threadIdx.x;
    for (int i = t; i < NBUCKETS; i += 1024) hist[i] = 0;
    __syncthreads();
    int e0 = blockIdx.x * CE;
    for (int e = e0 + t; e < e0 + CE; e += 1024) {
        atomicAdd(&hist[dst[e] >> 6], 1);
    }
    __syncthreads();
    for (int i = t; i < NBUCKETS; i += 1024) {
        counts[i * NCHUNK + blockIdx.x] = hist[i];
    }
}

__global__ __launch_bounds__(1024) void scan1_kernel(const int* __restrict__ in,
                                                     int* __restrict__ out,
                                                     int* __restrict__ blk_sums, int n) {
    __shared__ int s[1024];
    int t = threadIdx.x;
    int i = blockIdx.x * 1024 + t;
    int v = (i < n) ? in[i] : 0;
    s[t] = v;
    __syncthreads();
    for (int off = 1; off < 1024; off <<= 1) {
        int x = (t >= off) ? s[t - off] : 0;
        __syncthreads();
        s[t] += x;
        __syncthreads();
    }
    int incl = s[t];
    if (i < n) out[i] = incl - v;  // exclusive (block-local)
    if (t == 1023) blk_sums[blockIdx.x] = incl;
}

__global__ __launch_bounds__(256) void scan2_kernel(int* __restrict__ blk_sums, int nb) {
    __shared__ int s[256];
    int t = threadIdx.x;
    int v = (t < nb) ? blk_sums[t] : 0;
    s[t] = v;
    __syncthreads();
    for (int off = 1; off < 256; off <<= 1) {
        int x = (t >= off) ? s[t - off] : 0;
        __syncthreads();
        s[t] += x;
        __syncthreads();
    }
    if (t < nb) blk_sums[t] = s[t] - v;  // exclusive
}

__global__ __launch_bounds__(1024) void scan3_kernel(int* __restrict__ out,
                                                     const int* __restrict__ blk_sums, int n) {
    int i = blockIdx.x * 1024 + threadIdx.x;
    if (i < n) out[i] += blk_sums[blockIdx.x];
}

__global__ __launch_bounds__(1024) void scatter2_kernel(const int* __restrict__ src,
                                                        const int* __restrict__ dst,
                                                        const float* __restrict__ w,
                                                        const int* __restrict__ scanned,
                                                        int2* __restrict__ tmp) {
    __shared__ int cur[NBUCKETS];
    int t = threadIdx.x;
    for (int i = t; i < NBUCKETS; i += 1024) {
        cur[i] = scanned[i * NCHUNK + blockIdx.x];
    }
    __syncthreads();
    int e0 = blockIdx.x * CE;
    for (int e = e0 + t; e < e0 + CE; e += 1024) {
        int d = dst[e];
        int p = atomicAdd(&cur[d >> 6], 1);  // LDS atomic
        int2 v;
        v.x = ((d & 63) << 16) | src[e];
        v.y = __float_as_int(w[e]);
        tmp[p] = v;
    }
}

// one block per bucket: node-level histogram + scan in LDS -> final CSR order
// (4-byte packed edges); also writes row_ptr for the bucket's 64 nodes.
__global__ __launch_bounds__(256) void sort2_kernel(const int* __restrict__ scanned,
                                                    const int2* __restrict__ tmp,
                                                    unsigned int* __restrict__ edges4,
                                                    int* __restrict__ row_ptr) {
    __shared__ int hist[NPB];
    __shared__ int cur[NPB];
    int b = blockIdx.x;
    int t = threadIdx.x;
    int estart = scanned[b * NCHUNK];
    int eend = (b == NBUCKETS - 1) ? NEDGES : scanned[(b + 1) * NCHUNK];

    if (t < NPB) hist[t] = 0;
    __syncthreads();
    for (int e = estart + t; e < eend; e += 256) {
        atomicAdd(&hist[tmp[e].x >> 16], 1);  // LDS atomic
    }
    __syncthreads();
    if (t == 0) {
        int run = estart;
#pragma unroll
        for (int i = 0; i < NPB; ++i) {
            int c = hist[i];
            hist[i] = run;  // exclusive start
            run += c;
        }
    }
    __syncthreads();
    int nb0 = b * NPB;
    if (t < NPB) {
        int node = nb0 + t;
        if (node < NNODES) row_ptr[node] = hist[t];
        cur[t] = hist[t];
    }
    if (b == NBUCKETS - 1 && t == 0) row_ptr[NNODES] = NEDGES;
    __syncthreads();
    for (int e = estart + t; e < eend; e += 256) {
        int2 v = tmp[e];
        int loc = v.x >> 16;
        int p = atomicAdd(&cur[loc], 1);  // LDS atomic
        unsigned wb = (unsigned)v.y;
        unsigned r = (wb + 0x7FFFu + ((wb >> 16) & 1u)) >> 16;  // RNE to bf16
        edges4[p] = (r << 16) | (unsigned)(v.x & 0xFFFF);
    }
}

// ---------------------------------------------------------------------------
// fp32 -> bf16 converts. Feature tables are STRIP-MAJOR: tab[s][node][32],
// strip s = feature f >> 5, so each 3.2 MB strip is a contiguous region
// (strips never share a cache line -> per-XCD L2 can hold one whole strip).
// The table is ALSO the hidden state h (bf16-only; no fp32 copy).
// ---------------------------------------------------------------------------

__global__ __launch_bounds__(256) void cvt_kernel(const float2* __restrict__ in,
                                                  __hip_bfloat162* __restrict__ outS,
                                                  int n2) {
    int i = blockIdx.x * 256 + threadIdx.x;
    int stride = gridDim.x * 256;
    for (; i < n2; i += stride) {
        float2 v = in[i];
        __hip_bfloat162 b;
        b.x = __float2bfloat16(v.x);
        b.y = __float2bfloat16(v.y);
        int n = i >> 6;
        int fp = i & 63;                 // float2-pair index within row
        outS[(size_t)(fp >> 4) * SELEMS2 + (size_t)n * 16 + (fp & 15)] = b;
    }
}

__global__ __launch_bounds__(256) void cvtw_kernel(const float* __restrict__ W0,
                                                   const float* __restrict__ Ws,
                                                   __hip_bfloat16* __restrict__ Wtb) {
    int idx = blockIdx.x * 256 + threadIdx.x;  // 0..65535 (4 matrices)
    int m = idx >> 14;
    int oi = idx & 16383;
    int n = oi >> 7;
    int k = oi & 127;
    const float* src = (m == 0) ? W0 : (Ws + (size_t)(m - 1) * NF * NF);
    Wtb[idx] = __float2bfloat16(src[k * NF + n]);
}

// ---------------------------------------------------------------------------
// SpMM, XCD-strip partitioned: blockIdx&7 -> XCD slot; strip = slot>>1.
// Each XCD gathers only its own 3.2 MB strip => L2-resident.
// Wave = 16 edges x 32 features: lane = (eg = lane>>2) edge group, (fq =
// lane&3) feature octet. Lane gathers 16 B (uint4 = 8 bf16) of its edge's
// 64-B strip row (4 lanes x 16 B = full row). 32-edge trips (2 rounds in
// flight). Full trips take a wave-uniform UNGUARDED fast path; only the
// tail trip pays the per-load guards (u = 0 => w = +0.0, row 0, exact).
// shfl_xor(4/8/16/32) reduces the 16 edge groups; lanes 0-3 store uint4.
// 1024-thread blocks (16 nodes each) cut dispatch count to 12504.
// ---------------------------------------------------------------------------

#define BF_LO(x) __uint_as_float((unsigned)(x) << 16)
#define BF_HI(x) __uint_as_float((unsigned)(x) & 0xFFFF0000u)

__global__ __launch_bounds__(1024) void spmm_kernel(const int* __restrict__ row_ptr,
                                                    const unsigned int* __restrict__ edges4,
                                                    const __hip_bfloat16* __restrict__ featS,
                                                    __hip_bfloat16* __restrict__ aggS) {
    int wave = threadIdx.x >> 6;         // 0..15
    int lane = threadIdx.x & 63;
    int xslot = blockIdx.x & 7;          // XCD (round-robin dispatch)
    int s = xslot >> 1;                  // feature strip 0..3
    int n = (blockIdx.x >> 3) * 32 + (xslot & 1) * 16 + wave;
    if (n >= NNODES) return;             // grid tail guard (wave-uniform)

    int e0 = __builtin_amdgcn_readfirstlane(row_ptr[n]);
    int e1 = __builtin_amdgcn_readfirstlane(row_ptr[n + 1]);

    int fq = lane & 3;                   // feature octet [fq*8, fq*8+8)
    int eg = lane >> 2;                  // edge group 0..15
    const __hip_bfloat16* tab = featS + (size_t)s * SELEMS + fq * 8;

    float a0 = 0.f, a1 = 0.f, a2 = 0.f, a3 = 0.f;
    float a4 = 0.f, a5 = 0.f, a6 = 0.f, a7 = 0.f;

    int e = e0;
    // full 32-edge trips: wave-uniform condition, unguarded loads
    for (; e + 32 <= e1; e += 32) {
        unsigned u0 = edges4[e + eg];
        unsigned u1 = edges4[e + 16 + eg];
        uint4 v0 = *(const uint4*)&tab[(size_t)(u0 & 0xFFFFu) * 32];
        uint4 v1 = *(const uint4*)&tab[(size_t)(u1 & 0xFFFFu) * 32];
        float w0 = __uint_as_float(u0 & 0xFFFF0000u);  // bf16<<16 IS the fp32
        float w1 = __uint_as_float(u1 & 0xFFFF0000u);
        a0 += w0 * BF_LO(v0.x); a1 += w0 * BF_HI(v0.x);
        a2 += w0 * BF_LO(v0.y); a3 += w0 * BF_HI(v0.y);
        a4 += w0 * BF_LO(v0.z); a5 += w0 * BF_HI(v0.z);
        a6 += w0 * BF_LO(v0.w); a7 += w0 * BF_HI(v0.w);
        a0 += w1 * BF_LO(v1.x); a1 += w1 * BF_HI(v1.x);
        a2 += w1 * BF_LO(v1.y); a3 += w1 * BF_HI(v1.y);
        a4 += w1 * BF_LO(v1.z); a5 += w1 * BF_HI(v1.z);
        a6 += w1 * BF_LO(v1.w); a7 += w1 * BF_HI(v1.w);
    }
    // tail trip (guarded)
    if (e < e1) {
        unsigned u0 = (e + eg < e1) ? edges4[e + eg] : 0u;
        unsigned u1 = (e + 16 + eg < e1) ? edges4[e + 16 + eg] : 0u;
        uint4 v0 = *(const uint4*)&tab[(size_t)(u0 & 0xFFFFu) * 32];
        uint4 v1 = *(const uint4*)&tab[(size_t)(u1 & 0xFFFFu) * 32];
        float w0 = __uint_as_float(u0 & 0xFFFF0000u);
        float w1 = __uint_as_float(u1 & 0xFFFF0000u);
        a0 += w0 * BF_LO(v0.x); a1 += w0 * BF_HI(v0.x);
        a2 += w0 * BF_LO(v0.y); a3 += w0 * BF_HI(v0.y);
        a4 += w0 * BF_LO(v0.z); a5 += w0 * BF_HI(v0.z);
        a6 += w0 * BF_LO(v0.w); a7 += w0 * BF_HI(v0.w);
        a0 += w1 * BF_LO(v1.x); a1 += w1 * BF_HI(v1.x);
        a2 += w1 * BF_LO(v1.y); a3 += w1 * BF_HI(v1.y);
        a4 += w1 * BF_LO(v1.z); a5 += w1 * BF_HI(v1.z);
        a6 += w1 * BF_LO(v1.w); a7 += w1 * BF_HI(v1.w);
    }

    // reduce across the 16 edge groups (lane bits 2..5)
#pragma unroll
    for (int off = 4; off < 64; off <<= 1) {
        a0 += __shfl_xor(a0, off);
        a1 += __shfl_xor(a1, off);
        a2 += __shfl_xor(a2, off);
        a3 += __shfl_xor(a3, off);
        a4 += __shfl_xor(a4, off);
        a5 += __shfl_xor(a5, off);
        a6 += __shfl_xor(a6, off);
        a7 += __shfl_xor(a7, off);
    }

    if (eg == 0) {
        __hip_bfloat162 q01, q23, q45, q67;
        q01.x = __float2bfloat16(a0); q01.y = __float2bfloat16(a1);
        q23.x = __float2bfloat16(a2); q23.y = __float2bfloat16(a3);
        q45.x = __float2bfloat16(a4); q45.y = __float2bfloat16(a5);
        q67.x = __float2bfloat16(a6); q67.y = __float2bfloat16(a7);
        uint4 o;
        o.x = *(unsigned*)&q01;
        o.y = *(unsigned*)&q23;
        o.z = *(unsigned*)&q45;
        o.w = *(unsigned*)&q67;
        *(uint4*)(aggS + (size_t)s * SELEMS + (size_t)n * 32 + fq * 8) = o;
    }
}

// ---------------------------------------------------------------------------
// MFMA bf16 GEMM, no LDS: tab[g][:] = relu(A[g][:] @ W + b) (+ tab residual,
// in-place same-thread RMW). A and tab are STRIP-MAJOR bf16 (strip = ks).
// C/D layout: col = lane&15, row = (lane>>4)*4 + reg   [m89-verified]
// ---------------------------------------------------------------------------

template <bool RES>
__global__ __launch_bounds__(256) void gemm_mfma_kernel(
    const __hip_bfloat16* __restrict__ A,    // strip-major [4][NNODES][32]
    const __hip_bfloat16* __restrict__ Wt,   // [n][k] bf16
    const float* __restrict__ bias,
    __hip_bfloat16* tab) {                   // strip-major table: res-in, h-out
    int t = threadIdx.x;
    int wave = t >> 6;
    int lane = t & 63;
    int lr = lane & 15;   // A-row / B-col / D-col within subtile
    int kg = lane >> 4;   // k-group (0..3)
    int row0 = blockIdx.x * 64 + wave * 16;

    int arow = row0 + lr;
    if (arow >= NNODES) arow = NNODES - 1;  // clamp; stores are guarded

    f32x4_t acc[8];
#pragma unroll
    for (int c = 0; c < 8; ++c) acc[c] = (f32x4_t){0.f, 0.f, 0.f, 0.f};

#pragma unroll
    for (int ks = 0; ks < 4; ++ks) {
        bf16x8_t af = *(const bf16x8_t*)&A[(size_t)ks * SELEMS + (size_t)arow * 32 + kg * 8];
#pragma unroll
        for (int c = 0; c < 8; ++c) {
            bf16x8_t bfr = *(const bf16x8_t*)&Wt[(size_t)(c * 16 + lr) * NF + ks * 32 + kg * 8];
            acc[c] = __builtin_amdgcn_mfma_f32_16x16x32_bf16(af, bfr, acc[c], 0, 0, 0);
        }
    }

    float bcol[8];
#pragma unroll
    for (int c = 0; c < 8; ++c) bcol[c] = bias[c * 16 + lr];

#pragma unroll
    for (int j = 0; j < 4; ++j) {
        int g = row0 + kg * 4 + j;
        if (g < NNODES) {
#pragma unroll
            for (int c = 0; c < 8; ++c) {
                int col = c * 16 + lr;
                size_t idx = (size_t)(col >> 5) * SELEMS + (size_t)g * 32 + (col & 31);
                float v = acc[c][j] + bcol[c];
                v = fmaxf(v, 0.f);
                if (RES) v += __bfloat162float(tab[idx]);
                tab[idx] = __float2bfloat16(v);
            }
        }
    }
}

// ---------------------------------------------------------------------------
// Head GEMM: out[N,40] = tab[N,128](bf16, strip-major) @ Wout + bout
// (fp32 accumulate, lW-only LDS)
// ---------------------------------------------------------------------------

__global__ __launch_bounds__(256) void head_kernel(const __hip_bfloat16* __restrict__ A,
                                                   const float* __restrict__ W,
                                                   const float* __restrict__ bias,
                                                   float* __restrict__ out) {
    __shared__ float lW[NF * NC];  // [k][j]
    int t = threadIdx.x;
    for (int idx = t * 4; idx < NF * NC; idx += 256 * 4) {
        *(float4*)&lW[idx] = *(const float4*)&W[idx];
    }
    __syncthreads();

    int m = t & 7;    // col group: cols m*5..m*5+4
    int rg = t >> 3;  // 0..31
    int row0 = blockIdx.x * 128 + rg * 4;

    float acc[4][5];
#pragma unroll
    for (int r = 0; r < 4; ++r)
#pragma unroll
        for (int j = 0; j < 5; ++j) acc[r][j] = 0.f;

    int gr[4];
#pragma unroll
    for (int r = 0; r < 4; ++r) {
        int g = row0 + r;
        gr[r] = g < NNODES ? g : NNODES - 1;
    }

    for (int k = 0; k < NF; k += 8) {
        int sIdx = k >> 5;
        int ko = k & 31;
        float af[4][8];
#pragma unroll
        for (int r = 0; r < 4; ++r) {
            uint4 av = *(const uint4*)&A[(size_t)sIdx * SELEMS + (size_t)gr[r] * 32 + ko];
            af[r][0] = BF_LO(av.x); af[r][1] = BF_HI(av.x);
            af[r][2] = BF_LO(av.y); af[r][3] = BF_HI(av.y);
            af[r][4] = BF_LO(av.z); af[r][5] = BF_HI(av.z);
            af[r][6] = BF_LO(av.w); af[r][7] = BF_HI(av.w);
        }
#pragma unroll
        for (int kk = 0; kk < 8; ++kk) {
            float wv[5];
#pragma unroll
            for (int j = 0; j < 5; ++j) wv[j] = lW[(k + kk) * NC + m * 5 + j];
#pragma unroll
            for (int r = 0; r < 4; ++r) {
#pragma unroll
                for (int j = 0; j < 5; ++j) acc[r][j] += af[r][kk] * wv[j];
            }
        }
    }

#pragma unroll
    for (int r = 0; r < 4; ++r) {
        int g = row0 + r;
        if (g < NNODES) {
#pragma unroll
            for (int j = 0; j < 5; ++j) {
                out[(size_t)g * NC + m * 5 + j] = acc[r][j] + bias[m * 5 + j];
            }
        }
    }
}

// ---------------------------------------------------------------------------

extern "C" void kernel_launch(void* const* d_in, const int* in_sizes, int n_in,
                              void* d_out, int out_size, void* d_ws, size_t ws_size,
                              hipStream_t stream) {
    const float* x    = (const float*)d_in[0];
    const int*   esrc = (const int*)d_in[1];
    const int*   edst = (const int*)d_in[2];
    const float* ew   = (const float*)d_in[3];
    const float* W0   = (const float*)d_in[4];
    const float* b0   = (const float*)d_in[5];
    const float* Ws   = (const float*)d_in[6];
    const float* bs   = (const float*)d_in[7];
    const float* Wout = (const float*)d_in[8];
    const float* bout = (const float*)d_in[9];
    float* out = (float*)d_out;

    // workspace carve (256-B aligned); total ~48 MB
    char* p = (char*)d_ws;
    auto alloc = [&](size_t bytes) -> void* {
        void* r = (void*)p;
        p += (bytes + 255) & ~(size_t)255;
        return r;
    };
    int*   row_ptr  = (int*)alloc((size_t)(NNODES + 1) * 4);
    int*   counts   = (int*)alloc((size_t)NSC * 4);
    int*   scanned  = (int*)alloc((size_t)NSC * 4);
    int*   blk_sums = (int*)alloc(256 * 4);
    int2*  tmp      = (int2*)alloc((size_t)NEDGES * 8);
    unsigned int* edges4 = (unsigned int*)alloc((size_t)NEDGES * 4);
    __hip_bfloat16* aggb = (__hip_bfloat16*)alloc((size_t)NNODES * NF * 2);
    __hip_bfloat16* hb   = (__hip_bfloat16*)alloc((size_t)NNODES * NF * 2);
    __hip_bfloat16* Wtb  = (__hip_bfloat16*)alloc((size_t)4 * NF * NF * 2);

    const int nb_sc = (NSC + 1023) / 1024;        // 196
    const int spmm_grid = 12504;                  // ceil(50000/32)*8
    const int gemm_grid = (NNODES + 63) / 64;     // 782
    const int head_grid = (NNODES + 127) / 128;   // 391

    // ---- CSR build: counting sort by bucket, then per-bucket node sort ----
    count_kernel<<<NCHUNK, 1024, 0, stream>>>(edst, counts);
    scan1_kernel<<<nb_sc, 1024, 0, stream>>>(counts, scanned, blk_sums, NSC);
    scan2_kernel<<<1, 256, 0, stream>>>(blk_sums, nb_sc);
    scan3_kernel<<<nb_sc, 1024, 0, stream>>>(scanned, blk_sums, NSC);
    scatter2_kernel<<<NCHUNK, 1024, 0, stream>>>(esrc, edst, ew, scanned, tmp);
    sort2_kernel<<<NBUCKETS, 256, 0, stream>>>(scanned, tmp, edges4, row_ptr);

    // ---- converts: x -> strip-major bf16 table; weights -> bf16 W^T ----
    cvt_kernel<<<2048, 256, 0, stream>>>((const float2*)x, (__hip_bfloat162*)hb, NNODES * 64);
    cvtw_kernel<<<256, 256, 0, stream>>>(W0, Ws, Wtb);

    // ---- layer 0: table = relu(spmm(table) @ W0 + b0) ----
    spmm_kernel<<<spmm_grid, 1024, 0, stream>>>(row_ptr, edges4, hb, aggb);
    gemm_mfma_kernel<false><<<gemm_grid, 256, 0, stream>>>(aggb, Wtb, b0, hb);

    // ---- residual layers (in-place bf16 residual on the table) ----
    for (int l = 0; l < NLAYERS; ++l) {
        spmm_kernel<<<spmm_grid, 1024, 0, stream>>>(row_ptr, edges4, hb, aggb);
        gemm_mfma_kernel<true>
            <<<gemm_grid, 256, 0, stream>>>(aggb, Wtb + (size_t)(l + 1) * NF * NF,
                                            bs + (size_t)l * NF, hb);
    }

    // ---- output head ----
    head_kernel<<<head_grid, 256, 0, stream>>>(hb, Wout, bout, out);
}